// Round 1
// baseline (57.815 us; speedup 1.0000x reference)
//
#include <hip/hip_runtime.h>

#define KW   7
#define PAD  3
#define CIN  64
#define COUT 64
#define HH   64
#define WW   64
#define BB   4
#define HP   70   // HH + 2*PAD
#define WP   70

// ---------------------------------------------------------------------------
// Kernel 1: q / k_full / v_full projections.
// Grid: (ceil(HP*WP/256), COUT, BB). Block-uniform o -> weight reads become
// scalar loads. k/v computed over the padded grid (pad positions write 0.0f,
// matching pad-then-conv in the reference). q only on the interior.
// ---------------------------------------------------------------------------
__global__ __launch_bounds__(256) void qkv_kernel(
    const float* __restrict__ x,  const float* __restrict__ wq,
    const float* __restrict__ wk, const float* __restrict__ wv,
    float* __restrict__ qb, float* __restrict__ kb, float* __restrict__ vb)
{
    const int o = blockIdx.y;
    const int b = blockIdx.z;
    const int p = blockIdx.x * blockDim.x + threadIdx.x;
    if (p >= HP * WP) return;
    const int hp = p / WP;
    const int wp = p - hp * WP;
    const bool interior = (hp >= PAD) & (hp < PAD + HH) & (wp >= PAD) & (wp < PAD + WW);

    float qa = 0.f, ka = 0.f, va = 0.f;
    if (interior) {
        const int h = hp - PAD, w = wp - PAD;
        const float* xp = x + ((size_t)b * CIN * HH + h) * WW + w;
        const float* wqr = wq + o * CIN;
        const float* wkr = wk + o * CIN;
        const float* wvr = wv + o * CIN;
        #pragma unroll
        for (int c = 0; c < CIN; ++c) {
            const float xv = xp[(size_t)c * HH * WW];
            qa = fmaf(xv, wqr[c], qa);
            ka = fmaf(xv, wkr[c], ka);
            va = fmaf(xv, wvr[c], va);
        }
        qb[(((size_t)b * COUT + o) * HH + h) * WW + w] = qa;
    }
    kb[(((size_t)b * COUT + o) * HP + hp) * WP + wp] = ka;
    vb[(((size_t)b * COUT + o) * HP + hp) * WP + wp] = va;
}

// ---------------------------------------------------------------------------
// Kernel 2: per-channel 7x7 local attention.
// Block = (64,4): one wave per output row (lane = w, coalesced + L1-hot
// neighborhood reads within the (b,o) 19.6KB plane). Logits kept in 49
// fully-unrolled registers; two-pass stable softmax.
// ---------------------------------------------------------------------------
__global__ __launch_bounds__(256) void attn_kernel(
    const float* __restrict__ qb, const float* __restrict__ kb,
    const float* __restrict__ vb, const float* __restrict__ rel_h,
    const float* __restrict__ rel_w, float* __restrict__ out)
{
    const int w    = threadIdx.x;                 // 0..63
    const int h    = blockIdx.x * 4 + threadIdx.y;
    const int o    = blockIdx.y;
    const int b    = blockIdx.z;
    const bool use_h = (o < COUT / 2);            // block-uniform

    float rel[KW];
    const float* relp = use_h ? (rel_h + o * KW) : (rel_w + (o - COUT / 2) * KW);
    #pragma unroll
    for (int t = 0; t < KW; ++t) rel[t] = relp[t];

    const float q = qb[(((size_t)b * COUT + o) * HH + h) * WW + w];
    const float* kplane = kb + ((size_t)b * COUT + o) * HP * WP;
    const float* vplane = vb + ((size_t)b * COUT + o) * HP * WP;

    float l[KW * KW];
    float m = -1e30f;
    #pragma unroll
    for (int i = 0; i < KW; ++i) {
        #pragma unroll
        for (int j = 0; j < KW; ++j) {
            const float kv = kplane[(h + i) * WP + (w + j)];
            const float r  = use_h ? rel[i] : rel[j];
            const float lo = q * (kv + r);
            l[i * KW + j] = lo;
            m = fmaxf(m, lo);
        }
    }

    float s = 0.f, acc = 0.f;
    #pragma unroll
    for (int i = 0; i < KW; ++i) {
        #pragma unroll
        for (int j = 0; j < KW; ++j) {
            const float e = __expf(l[i * KW + j] - m);
            s += e;
            acc = fmaf(e, vplane[(h + i) * WP + (w + j)], acc);
        }
    }
    out[(((size_t)b * COUT + o) * HH + h) * WW + w] = acc / s;
}

extern "C" void kernel_launch(void* const* d_in, const int* in_sizes, int n_in,
                              void* d_out, int out_size, void* d_ws, size_t ws_size,
                              hipStream_t stream) {
    const float* x     = (const float*)d_in[0];
    const float* wq    = (const float*)d_in[1];
    const float* wk    = (const float*)d_in[2];
    const float* wv    = (const float*)d_in[3];
    const float* rel_h = (const float*)d_in[4];
    const float* rel_w = (const float*)d_in[5];
    float* out = (float*)d_out;

    float* qb = (float*)d_ws;                        // BB*COUT*HH*WW   = 1,048,576 f
    float* kb = qb + (size_t)BB * COUT * HH * WW;    // BB*COUT*HP*WP   = 1,254,400 f
    float* vb = kb + (size_t)BB * COUT * HP * WP;    // BB*COUT*HP*WP   = 1,254,400 f

    dim3 g1((HP * WP + 255) / 256, COUT, BB);
    qkv_kernel<<<g1, 256, 0, stream>>>(x, wq, wk, wv, qb, kb, vb);

    dim3 g2(HH / 4, COUT, BB);
    dim3 b2(64, 4);
    attn_kernel<<<g2, b2, 0, stream>>>(qb, kb, vb, rel_h, rel_w, out);
}

// Round 2
// 30.622 us; speedup vs baseline: 1.8880x; 1.8880x over previous
//
#include <hip/hip_runtime.h>

#define KW   7
#define PAD  3
#define CIN  64
#define COUT 64
#define HH   64
#define WW   64
#define BB   4
#define HW   (HH * WW)

// ---------------------------------------------------------------------------
// Kernel 1: q / k / v 1x1-conv projections, interior only.
// Padded positions of k_full/v_full are exactly 0 (1x1 conv of zero pad, no
// bias), so we never materialize them — K2 synthesizes the zeros.
// Grid: (16 pixel-tiles, 16 o-groups, B). Block-uniform o-group -> weight
// reads are scalar (s_load). Each x value is loaded once and feeds 12 FMAs.
// ---------------------------------------------------------------------------
__global__ __launch_bounds__(256) void qkv_kernel(
    const float* __restrict__ x,  const float* __restrict__ wq,
    const float* __restrict__ wk, const float* __restrict__ wv,
    float* __restrict__ qb, float* __restrict__ kb, float* __restrict__ vb)
{
    const int t  = threadIdx.x;
    const int b  = blockIdx.z;
    const int og = blockIdx.y * 4;            // 4 output channels per block
    const int p  = blockIdx.x * 256 + t;      // interior pixel (h*64+w)

    const float* xp  = x + (size_t)b * CIN * HW + p;
    const float* wqr = wq + og * CIN;
    const float* wkr = wk + og * CIN;
    const float* wvr = wv + og * CIN;

    float qa[4] = {0.f, 0.f, 0.f, 0.f};
    float ka[4] = {0.f, 0.f, 0.f, 0.f};
    float va[4] = {0.f, 0.f, 0.f, 0.f};

    #pragma unroll
    for (int c = 0; c < CIN; ++c) {
        const float xv = xp[(size_t)c * HW];
        #pragma unroll
        for (int oo = 0; oo < 4; ++oo) {
            qa[oo] = fmaf(xv, wqr[oo * CIN + c], qa[oo]);
            ka[oo] = fmaf(xv, wkr[oo * CIN + c], ka[oo]);
            va[oo] = fmaf(xv, wvr[oo * CIN + c], va[oo]);
        }
    }

    #pragma unroll
    for (int oo = 0; oo < 4; ++oo) {
        const size_t idx = ((size_t)b * COUT + og + oo) * HW + p;
        qb[idx] = qa[oo];
        kb[idx] = ka[oo];
        vb[idx] = va[oo];
    }
}

// ---------------------------------------------------------------------------
// Kernel 2: per-channel 7x7 local attention.
// Block (64,4) = 4 output rows of one (b,o) plane. k/v halo rows staged in
// LDS with zero borders (replaces bounds masks AND the padded global planes).
// Softmax without max-subtraction (|logit|<~60 -> exp2 arg <87, safe in f32):
//   e = exp2(q*log2e * k  +  q*log2e * rel)   — rel term precomputed per row
// Inner position: 1 fma + 1 exp2 + 1 add + 1 fma + 2 conflict-free ds_reads.
// ---------------------------------------------------------------------------
__global__ __launch_bounds__(256) void attn_kernel(
    const float* __restrict__ qb, const float* __restrict__ kb,
    const float* __restrict__ vb, const float* __restrict__ rel_h,
    const float* __restrict__ rel_w, float* __restrict__ out)
{
    __shared__ float kt[10][72];
    __shared__ float vt[10][72];

    const int tx = threadIdx.x;               // w: 0..63 (lane)
    const int ty = threadIdx.y;               // row within tile: 0..3
    const int h0 = blockIdx.x * 4;
    const int o  = blockIdx.y;
    const int b  = blockIdx.z;
    const size_t plane = ((size_t)b * COUT + o) * HW;

    // Stage k/v rows h0-3 .. h0+6 (10 rows), zero outside the interior.
    for (int rr = ty; rr < 10; rr += 4) {
        const int gr = h0 - 3 + rr;
        float kk = 0.f, vv = 0.f;
        if (gr >= 0 && gr < HH) {
            kk = kb[plane + (size_t)gr * WW + tx];
            vv = vb[plane + (size_t)gr * WW + tx];
        }
        kt[rr][tx + 3] = kk;
        vt[rr][tx + 3] = vv;
        if (tx < 3) {                          // zero left/right halo columns
            kt[rr][tx] = 0.f;      vt[rr][tx] = 0.f;
            kt[rr][tx + 67] = 0.f; vt[rr][tx + 67] = 0.f;
        }
    }
    __syncthreads();

    const float q  = qb[plane + (size_t)(h0 + ty) * WW + tx];
    const float q2 = q * 1.44269504088896f;   // fold log2(e) into q

    const bool use_h = (o < COUT / 2);        // block-uniform
    const float* rp = use_h ? (rel_h + o * KW) : (rel_w + (o - COUT / 2) * KW);
    float qadd[KW];
    #pragma unroll
    for (int t = 0; t < KW; ++t) qadd[t] = q2 * rp[t];

    float s = 0.f, acc = 0.f;
    if (use_h) {                               // rel indexed by window ROW
        #pragma unroll
        for (int i = 0; i < KW; ++i) {
            #pragma unroll
            for (int j = 0; j < KW; ++j) {
                const float e = __builtin_amdgcn_exp2f(
                    fmaf(q2, kt[ty + i][tx + j], qadd[i]));
                s += e;
                acc = fmaf(e, vt[ty + i][tx + j], acc);
            }
        }
    } else {                                   // rel indexed by window COLUMN
        #pragma unroll
        for (int i = 0; i < KW; ++i) {
            #pragma unroll
            for (int j = 0; j < KW; ++j) {
                const float e = __builtin_amdgcn_exp2f(
                    fmaf(q2, kt[ty + i][tx + j], qadd[j]));
                s += e;
                acc = fmaf(e, vt[ty + i][tx + j], acc);
            }
        }
    }

    out[plane + (size_t)(h0 + ty) * WW + tx] = acc / s;
}

extern "C" void kernel_launch(void* const* d_in, const int* in_sizes, int n_in,
                              void* d_out, int out_size, void* d_ws, size_t ws_size,
                              hipStream_t stream) {
    const float* x     = (const float*)d_in[0];
    const float* wq    = (const float*)d_in[1];
    const float* wk    = (const float*)d_in[2];
    const float* wv    = (const float*)d_in[3];
    const float* rel_h = (const float*)d_in[4];
    const float* rel_w = (const float*)d_in[5];
    float* out = (float*)d_out;

    float* qb = (float*)d_ws;                 // BB*COUT*HW = 1,048,576 floats
    float* kb = qb + (size_t)BB * COUT * HW;
    float* vb = kb + (size_t)BB * COUT * HW;

    dim3 g1(HW / 256, COUT / 4, BB);          // (16, 16, 4)
    qkv_kernel<<<g1, 256, 0, stream>>>(x, wq, wk, wv, qb, kb, vb);

    dim3 g2(HH / 4, COUT, BB);                // (16, 64, 4)
    dim3 b2(64, 4);
    attn_kernel<<<g2, b2, 0, stream>>>(qb, kb, vb, rel_h, rel_w, out);
}